// Round 1
// baseline (247.846 us; speedup 1.0000x reference)
//
#include <hip/hip_runtime.h>
#include <math.h>

// Model dims: B=1024, S=16, E=32, NH=4, H=64 (lstm1), H/2=32 (lstm2)

__device__ __forceinline__ float sigf(float x) { return 1.0f / (1.0f + __expf(-x)); }
__device__ __forceinline__ float tanh_f(float x) {
    float a = fabsf(x);
    float e = __expf(2.0f * a);
    float t = 1.0f - 2.0f / (e + 1.0f);   // safe: e->inf => t->1
    return copysignf(t, x);
}

// ---------------- prep: fold embedding + pos-enc + biases into A1[256], C1[16][256]
__global__ void prep_kernel(const float* __restrict__ emb_w, const float* __restrict__ emb_b,
                            const float* __restrict__ wih1, const float* __restrict__ bih1,
                            const float* __restrict__ bhh1,
                            float* __restrict__ A1, float* __restrict__ C1) {
    int t = threadIdx.x;  // gate index 0..255
    float a = 0.f;
#pragma unroll
    for (int i = 0; i < 32; i++) a += emb_w[i] * wih1[t * 32 + i];
    A1[t] = a;
    float bb = bih1[t] + bhh1[t];
    for (int s = 0; s < 16; s++) {
        float c = bb;
#pragma unroll
        for (int i = 0; i < 32; i++) {
            int j = (i >> 1) * 2;
            float div = __expf(-logf(10000.0f) * (float)j / 32.0f);
            float ang = (float)s * div;
            float pe = (i & 1) ? __cosf(ang) : __sinf(ang);
            c += (emb_b[i] + pe) * wih1[t * 32 + i];
        }
        C1[s * 256 + t] = c;
    }
}

// ---------------- fused LSTM1 + LSTM2 + residual + QKV(n=15 slice). One block per batch elem.
__global__ __launch_bounds__(256) void lstm_kernel(
    const float* __restrict__ x,
    const float* __restrict__ whh1,   // 256x64
    const float* __restrict__ wih2,   // 128x64
    const float* __restrict__ whh2,   // 128x32
    const float* __restrict__ bih2, const float* __restrict__ bhh2,
    const float* __restrict__ attn_w, const float* __restrict__ attn_b,  // 96x32, 96
    const float* __restrict__ A1, const float* __restrict__ C1,
    float* __restrict__ Q, float* __restrict__ K, float* __restrict__ V) {
    int b = blockIdx.x;
    int t = threadIdx.x;
    __shared__ float h1s[64], h2s[32], g1s[256], g2s[128], xs[16], l2l[32];

    // register-resident recurrent weights
    float w1[64];
#pragma unroll
    for (int k = 0; k < 64; k++) w1[k] = whh1[t * 64 + k];
    float w2i[64];
    float w2h[32];
    float b2 = 0.f;
    if (t < 128) {
#pragma unroll
        for (int k = 0; k < 64; k++) w2i[k] = wih2[t * 64 + k];
#pragma unroll
        for (int k = 0; k < 32; k++) w2h[k] = whh2[t * 32 + k];
        b2 = bih2[t] + bhh2[t];
    }
    float A1t = A1[t];
    float C1r[16];
#pragma unroll
    for (int s = 0; s < 16; s++) C1r[s] = C1[s * 256 + t];

    if (t < 64) h1s[t] = 0.f;
    if (t >= 64 && t < 96) h2s[t - 64] = 0.f;
    if (t >= 96 && t < 112) xs[t - 96] = x[b * 16 + (t - 96)];
    float c1 = 0.f, c2 = 0.f;
    __syncthreads();

    for (int s = 0; s < 16; s++) {
        // LSTM1 gates: each of 256 threads computes one gate pre-activation
        float a0 = xs[s] * A1t + C1r[s], a1 = 0.f, a2 = 0.f, a3 = 0.f;
#pragma unroll
        for (int k = 0; k < 64; k += 4) {
            a0 += h1s[k] * w1[k];
            a1 += h1s[k + 1] * w1[k + 1];
            a2 += h1s[k + 2] * w1[k + 2];
            a3 += h1s[k + 3] * w1[k + 3];
        }
        g1s[t] = (a0 + a1) + (a2 + a3);
        __syncthreads();  // B1: gates ready; all done reading old h1s
        if (t < 64) {
            float gi = g1s[t], gf = g1s[t + 64], gg = g1s[t + 128], go = g1s[t + 192];
            c1 = sigf(gf) * c1 + sigf(gi) * tanh_f(gg);
            h1s[t] = sigf(go) * tanh_f(c1);
        }
        __syncthreads();  // B2: h1s updated
        // LSTM2 gates: threads 0..127
        if (t < 128) {
            float d0 = b2, d1 = 0.f, d2 = 0.f, d3 = 0.f;
#pragma unroll
            for (int k = 0; k < 64; k += 4) {
                d0 += h1s[k] * w2i[k];
                d1 += h1s[k + 1] * w2i[k + 1];
                d2 += h1s[k + 2] * w2i[k + 2];
                d3 += h1s[k + 3] * w2i[k + 3];
            }
#pragma unroll
            for (int k = 0; k < 32; k += 4) {
                d0 += h2s[k] * w2h[k];
                d1 += h2s[k + 1] * w2h[k + 1];
                d2 += h2s[k + 2] * w2h[k + 2];
                d3 += h2s[k + 3] * w2h[k + 3];
            }
            g2s[t] = (d0 + d1) + (d2 + d3);
        }
        __syncthreads();  // B3
        if (t < 32) {
            float gi = g2s[t], gf = g2s[t + 32], gg = g2s[t + 64], go = g2s[t + 96];
            c2 = sigf(gf) * c2 + sigf(gi) * tanh_f(gg);
            h2s[t] = sigf(go) * tanh_f(c2);
        }
        __syncthreads();  // B4: h2s updated before next step reads it
    }

    // residual at last step, then QKV projection (only n=15 slice is ever used)
    if (t < 32) l2l[t] = h2s[t] + h1s[t];
    __syncthreads();
    if (t < 96) {
        float acc = attn_b[t];
#pragma unroll
        for (int i = 0; i < 32; i++) acc += l2l[i] * attn_w[t * 32 + i];
        if (t < 32)
            Q[b * 32 + t] = acc * 0.35355339059327373f;  // 1/sqrt(8)
        else if (t < 64)
            K[b * 32 + (t - 32)] = acc;
        else
            V[b * 32 + (t - 64)] = acc;
    }
}

// ---------------- attention over the batch dim (head h, query l, key-chunk c of 128)
__global__ __launch_bounds__(256) void attn_kernel(
    const float* __restrict__ Q, const float* __restrict__ K, const float* __restrict__ V,
    float* __restrict__ pm, float* __restrict__ ps, float* __restrict__ pacc) {
    int g = blockIdx.x * 256 + threadIdx.x;  // 32768 threads
    int c = g >> 12;
    int h = (g >> 10) & 3;
    int l = g & 1023;
    const float* qp = Q + l * 32 + h * 8;
    float q[8];
#pragma unroll
    for (int d = 0; d < 8; d++) q[d] = qp[d];
    float m_r = -1e30f, l_r = 0.f;
    float acc[8];
#pragma unroll
    for (int d = 0; d < 8; d++) acc[d] = 0.f;
    int m0 = c * 128;
    for (int mm = 0; mm < 128; mm++) {
        int m = m0 + mm;
        const float* kp = K + m * 32 + h * 8;
        float s = 0.f;
#pragma unroll
        for (int d = 0; d < 8; d++) s += q[d] * kp[d];
        const float* vp = V + m * 32 + h * 8;
        float nm = fmaxf(m_r, s);
        float f = __expf(m_r - nm);
        float p = __expf(s - nm);
        l_r = l_r * f + p;
#pragma unroll
        for (int d = 0; d < 8; d++) acc[d] = acc[d] * f + p * vp[d];
        m_r = nm;
    }
    int idx = (c * 4 + h) * 1024 + l;
    pm[idx] = m_r;
    ps[idx] = l_r;
#pragma unroll
    for (int d = 0; d < 8; d++) pacc[idx * 8 + d] = acc[d];
}

// ---------------- combine chunks + attn out-proj + MLP head + sigmoid. One wave per l.
__global__ __launch_bounds__(256) void head_kernel(
    const float* __restrict__ pm, const float* __restrict__ ps, const float* __restrict__ pacc,
    const float* __restrict__ ow, const float* __restrict__ ob,
    const float* __restrict__ d1w, const float* __restrict__ d1b,
    const float* __restrict__ g1, const float* __restrict__ b1,
    const float* __restrict__ d2w, const float* __restrict__ d2b,
    const float* __restrict__ g2, const float* __restrict__ b2,
    const float* __restrict__ d3w, const float* __restrict__ d3b,
    float* __restrict__ out) {
    int wid = threadIdx.x >> 6, j = threadIdx.x & 63;
    int l = blockIdx.x * 4 + wid;
    __shared__ float att_s[4][32], z_s[4][32], r1s[4][64];
    if (j < 32) {
        int h = j >> 3, d = j & 7;
        float M = -1e30f;
#pragma unroll
        for (int c = 0; c < 8; c++) M = fmaxf(M, pm[(c * 4 + h) * 1024 + l]);
        float den = 0.f, num = 0.f;
#pragma unroll
        for (int c = 0; c < 8; c++) {
            int idx = (c * 4 + h) * 1024 + l;
            float e = __expf(pm[idx] - M);
            den += e * ps[idx];
            num += e * pacc[idx * 8 + d];
        }
        att_s[wid][j] = num / den;
    }
    __syncthreads();
    if (j < 32) {
        float a = ob[j];
#pragma unroll
        for (int i = 0; i < 32; i++) a += att_s[wid][i] * ow[j * 32 + i];
        z_s[wid][j] = a;
    }
    __syncthreads();
    const float inv = rsqrtf(1.0f + 1e-5f);
    if (j < 64) {
        float a = d1b[j];
#pragma unroll
        for (int i = 0; i < 32; i++) a += z_s[wid][i] * d1w[j * 32 + i];
        a = a * (g1[j] * inv) + b1[j];
        r1s[wid][j] = fmaxf(a, 0.f);
    }
    __syncthreads();
    if (j < 32) {
        float a = d2b[j];
#pragma unroll
        for (int i = 0; i < 64; i++) a += r1s[wid][i] * d2w[j * 64 + i];
        a = a * (g2[j] * inv) + b2[j];
        float r2 = fmaxf(a, 0.f);
        float p = r2 * d3w[j];
        p += __shfl_down(p, 16);
        p += __shfl_down(p, 8);
        p += __shfl_down(p, 4);
        p += __shfl_down(p, 2);
        p += __shfl_down(p, 1);
        if (j == 0) out[l] = 1.0f / (1.0f + __expf(-(p + d3b[0])));
    }
}

extern "C" void kernel_launch(void* const* d_in, const int* in_sizes, int n_in,
                              void* d_out, int out_size, void* d_ws, size_t ws_size,
                              hipStream_t stream) {
    const float* x      = (const float*)d_in[0];
    const float* emb_w  = (const float*)d_in[1];
    const float* emb_b  = (const float*)d_in[2];
    const float* l1_wih = (const float*)d_in[3];
    const float* l1_whh = (const float*)d_in[4];
    const float* l1_bih = (const float*)d_in[5];
    const float* l1_bhh = (const float*)d_in[6];
    const float* l2_wih = (const float*)d_in[7];
    const float* l2_whh = (const float*)d_in[8];
    const float* l2_bih = (const float*)d_in[9];
    const float* l2_bhh = (const float*)d_in[10];
    const float* attn_w = (const float*)d_in[11];
    const float* attn_b = (const float*)d_in[12];
    const float* attn_ow = (const float*)d_in[13];
    const float* attn_ob = (const float*)d_in[14];
    const float* d1_w  = (const float*)d_in[15];
    const float* d1_b  = (const float*)d_in[16];
    const float* bn1_g = (const float*)d_in[17];
    const float* bn1_b = (const float*)d_in[18];
    const float* d2_w  = (const float*)d_in[19];
    const float* d2_b  = (const float*)d_in[20];
    const float* bn2_g = (const float*)d_in[21];
    const float* bn2_b = (const float*)d_in[22];
    const float* d3_w  = (const float*)d_in[23];
    const float* d3_b  = (const float*)d_in[24];
    float* out = (float*)d_out;

    float* ws   = (float*)d_ws;
    float* A1   = ws;              // 256
    float* C1   = ws + 256;        // 16*256 = 4096
    float* Q    = ws + 4352;       // 1024*32
    float* K    = ws + 37120;      // 1024*32
    float* V    = ws + 69888;      // 1024*32
    float* pm   = ws + 102656;     // 8*4*1024
    float* ps   = ws + 135424;     // 8*4*1024
    float* pacc = ws + 168192;     // 8*4*1024*8
    // total 430336 floats ~= 1.72 MB

    prep_kernel<<<1, 256, 0, stream>>>(emb_w, emb_b, l1_wih, l1_bih, l1_bhh, A1, C1);
    lstm_kernel<<<1024, 256, 0, stream>>>(x, l1_whh, l2_wih, l2_whh, l2_bih, l2_bhh,
                                          attn_w, attn_b, A1, C1, Q, K, V);
    attn_kernel<<<128, 256, 0, stream>>>(Q, K, V, pm, ps, pacc);
    head_kernel<<<256, 256, 0, stream>>>(pm, ps, pacc, attn_ow, attn_ob, d1_w, d1_b,
                                         bn1_g, bn1_b, d2_w, d2_b, bn2_g, bn2_b,
                                         d3_w, d3_b, out);
}

// Round 2
// 159.615 us; speedup vs baseline: 1.5528x; 1.5528x over previous
//
#include <hip/hip_runtime.h>
#include <math.h>

// Model dims: B=1024, S=16, E=32, NH=4, H=64 (lstm1), 32 (lstm2)

__device__ __forceinline__ float sigf(float x) { return 1.0f / (1.0f + __expf(-x)); }
__device__ __forceinline__ float tanh_f(float x) {
    float a = fabsf(x);
    float e = __expf(2.0f * a);
    float t = 1.0f - 2.0f / (e + 1.0f);
    return copysignf(t, x);
}

// ---------------- prep: fold embedding + pos-enc + biases into A1[256], C1[16][256]
// grid 16 (one block per s), block 256 (one thread per gate)
__global__ void prep_kernel(const float* __restrict__ emb_w, const float* __restrict__ emb_b,
                            const float* __restrict__ wih1, const float* __restrict__ bih1,
                            const float* __restrict__ bhh1,
                            float* __restrict__ A1, float* __restrict__ C1) {
    int s = blockIdx.x, t = threadIdx.x;
    float c = bih1[t] + bhh1[t];
#pragma unroll
    for (int i = 0; i < 32; i++) {
        int j = (i >> 1) * 2;
        float div = __expf(-0.28782313662425574f * (float)j);  // -ln(10000)/32 * j
        float ang = (float)s * div;
        float pe = (i & 1) ? __cosf(ang) : __sinf(ang);
        c += (emb_b[i] + pe) * wih1[t * 32 + i];
    }
    C1[s * 256 + t] = c;
    if (s == 0) {
        float a = 0.f;
#pragma unroll
        for (int i = 0; i < 32; i++) a += emb_w[i] * wih1[t * 32 + i];
        A1[t] = a;
    }
}

// ---------------- fused LSTM1+LSTM2+residual+QKV. 2 batch elems per block, 512 blocks.
__global__ __launch_bounds__(256, 2) void lstm_kernel(
    const float* __restrict__ x,
    const float* __restrict__ whh1,   // 256x64
    const float* __restrict__ wih2,   // 128x64
    const float* __restrict__ whh2,   // 128x32
    const float* __restrict__ bih2, const float* __restrict__ bhh2,
    const float* __restrict__ attn_w, const float* __restrict__ attn_b,  // 96x32, 96
    const float* __restrict__ A1, const float* __restrict__ C1,
    float* __restrict__ Q, float* __restrict__ K, float* __restrict__ V) {
    int t = threadIdx.x;
    int base = blockIdx.x * 2;
    __shared__ __align__(16) float h1s[2][2][64];   // [parity][b][unit]
    __shared__ __align__(16) float h2s[2][2][32];
    __shared__ __align__(16) float g1s[2][256];     // [b][gate]
    __shared__ __align__(16) float g2p[2][2][128];  // [b][half][gate]
    __shared__ __align__(16) float l2l[2][32];
    __shared__ float xs[2][16];

    // thread t owns whh1 row t (64 regs)
    float w1[64];
#pragma unroll
    for (int k = 0; k < 64; k++) w1[k] = whh1[t * 64 + k];
    // LSTM2: gate g = t&127, k-half = t>>7 (48 regs)
    int g = t & 127, half = t >> 7;
    float w2a[32];
#pragma unroll
    for (int k = 0; k < 32; k++) w2a[k] = wih2[g * 64 + half * 32 + k];
    float w2b[16];
#pragma unroll
    for (int k = 0; k < 16; k++) w2b[k] = whh2[g * 32 + half * 16 + k];
    float A1t = A1[t];
    float C1r[16];
#pragma unroll
    for (int s = 0; s < 16; s++) C1r[s] = C1[s * 256 + t];
    int j2 = t & 31;
    float bi2 = bih2[j2] + bhh2[j2];
    float bf2 = bih2[32 + j2] + bhh2[32 + j2];
    float bg2 = bih2[64 + j2] + bhh2[64 + j2];
    float bo2 = bih2[96 + j2] + bhh2[96 + j2];

    if (t < 128) h1s[0][t >> 6][t & 63] = 0.f;
    if (t < 64) h2s[0][t >> 5][t & 31] = 0.f;
    if (t < 32) xs[t >> 4][t & 15] = x[(base + (t >> 4)) * 16 + (t & 15)];
    float c1 = 0.f, c2 = 0.f;
    __syncthreads();

#pragma unroll
    for (int s = 0; s < 16; s++) {
        const int p = s & 1, pn = p ^ 1;
        // ---- A: LSTM1 gate pre-acts (all 256 threads, both batches)
        {
            const float4* h0 = (const float4*)h1s[p][0];
            const float4* h1 = (const float4*)h1s[p][1];
            float a0 = xs[0][s] * A1t + C1r[s];
            float a1 = xs[1][s] * A1t + C1r[s];
#pragma unroll
            for (int k4 = 0; k4 < 16; k4++) {
                float4 u = h0[k4];
                float4 v = h1[k4];
                a0 += u.x * w1[4 * k4] + u.y * w1[4 * k4 + 1] + u.z * w1[4 * k4 + 2] + u.w * w1[4 * k4 + 3];
                a1 += v.x * w1[4 * k4] + v.y * w1[4 * k4 + 1] + v.z * w1[4 * k4 + 2] + v.w * w1[4 * k4 + 3];
            }
            g1s[0][t] = a0;
            g1s[1][t] = a1;
        }
        __syncthreads();  // B1: g1s ready
        // ---- B: LSTM1 activations (threads 0..127 = (b,j))
        if (t < 128) {
            int b = t >> 6, j = t & 63;
            float gi = g1s[b][j], gf = g1s[b][64 + j], gg = g1s[b][128 + j], go = g1s[b][192 + j];
            c1 = sigf(gf) * c1 + sigf(gi) * tanh_f(gg);
            h1s[pn][b][j] = sigf(go) * tanh_f(c1);
        }
        __syncthreads();  // B2: new h1 ready
        // ---- C: LSTM2 gate partials (all 256 threads: gate g, k-half)
        {
#pragma unroll
            for (int b = 0; b < 2; b++) {
                const float4* hn = (const float4*)(&h1s[pn][b][half * 32]);
                const float4* ho = (const float4*)(&h2s[p][b][half * 16]);
                float d0 = 0.f, d1 = 0.f;
#pragma unroll
                for (int k4 = 0; k4 < 8; k4++) {
                    float4 u = hn[k4];
                    d0 += u.x * w2a[4 * k4] + u.y * w2a[4 * k4 + 1] + u.z * w2a[4 * k4 + 2] + u.w * w2a[4 * k4 + 3];
                }
#pragma unroll
                for (int k4 = 0; k4 < 4; k4++) {
                    float4 u = ho[k4];
                    d1 += u.x * w2b[4 * k4] + u.y * w2b[4 * k4 + 1] + u.z * w2b[4 * k4 + 2] + u.w * w2b[4 * k4 + 3];
                }
                g2p[b][half][g] = d0 + d1;
            }
        }
        __syncthreads();  // B3: g2 partials ready
        // ---- D: LSTM2 activations (threads 0..63 = (b,j2))
        if (t < 64) {
            int b = t >> 5, j = t & 31;
            float gi = g2p[b][0][j] + g2p[b][1][j] + bi2;
            float gf = g2p[b][0][32 + j] + g2p[b][1][32 + j] + bf2;
            float gg = g2p[b][0][64 + j] + g2p[b][1][64 + j] + bg2;
            float go = g2p[b][0][96 + j] + g2p[b][1][96 + j] + bo2;
            c2 = sigf(gf) * c2 + sigf(gi) * tanh_f(gg);
            h2s[pn][b][j] = sigf(go) * tanh_f(c2);
        }
        // no barrier: next iteration's B1 orders D's h2s writes before C(s+1) reads
    }

    __syncthreads();  // final h states (parity 0) ready
    if (t < 64) {
        int b = t >> 5, j = t & 31;
        l2l[b][j] = h2s[0][b][j] + h1s[0][b][j];
    }
    __syncthreads();
    // QKV projection for the n=15 slice only
    if (t < 192) {
        int b = (t >= 96), r = t - b * 96;
        const float4* lw = (const float4*)l2l[b];
        const float4* aw = (const float4*)(attn_w + r * 32);
        float acc = attn_b[r];
#pragma unroll
        for (int k4 = 0; k4 < 8; k4++) {
            float4 u = lw[k4], w = aw[k4];
            acc += u.x * w.x + u.y * w.y + u.z * w.z + u.w * w.w;
        }
        int gb = base + b;
        if (r < 32) Q[gb * 32 + r] = acc * 0.35355339059327373f;  // 1/sqrt(8)
        else if (r < 64) K[gb * 32 + (r - 32)] = acc;
        else V[gb * 32 + (r - 64)] = acc;
    }
}

// ---------------- attention over batch dim. 16 chunks x 16 l-tiles = 256 blocks.
// block: (c, lt); threads: h = t>>6 (wave-uniform), l = lt*64 + (t&63)
__global__ __launch_bounds__(256, 2) void attn_kernel(
    const float* __restrict__ Q, const float* __restrict__ K, const float* __restrict__ V,
    float* __restrict__ pm, float* __restrict__ ps, float* __restrict__ pacc) {
    int c = blockIdx.x & 15, lt = blockIdx.x >> 4;
    int t = threadIdx.x;
    int h = t >> 6, l = lt * 64 + (t & 63);
    __shared__ __align__(16) float Ks[64 * 32];
    __shared__ __align__(16) float Vs[64 * 32];
    {
        const float4* Kg = (const float4*)(K + c * 2048);
        const float4* Vg = (const float4*)(V + c * 2048);
        float4* K4 = (float4*)Ks;
        float4* V4 = (float4*)Vs;
        K4[t] = Kg[t];
        K4[t + 256] = Kg[t + 256];
        V4[t] = Vg[t];
        V4[t + 256] = Vg[t + 256];
    }
    const float4* qg = (const float4*)(Q + l * 32 + h * 8);
    float4 q0 = qg[0], q1 = qg[1];
    __syncthreads();
    float m_r = -1e30f, l_r = 0.f;
    float4 acc0 = {0, 0, 0, 0}, acc1 = {0, 0, 0, 0};
#pragma unroll 4
    for (int m = 0; m < 64; m++) {
        const float4* k4 = (const float4*)(Ks + m * 32 + h * 8);
        float4 ka = k4[0], kb = k4[1];
        float s = q0.x * ka.x + q0.y * ka.y + q0.z * ka.z + q0.w * ka.w +
                  q1.x * kb.x + q1.y * kb.y + q1.z * kb.z + q1.w * kb.w;
        const float4* v4 = (const float4*)(Vs + m * 32 + h * 8);
        float4 va = v4[0], vb = v4[1];
        float nm = fmaxf(m_r, s);
        float f = __expf(m_r - nm);
        float pp = __expf(s - nm);
        l_r = l_r * f + pp;
        acc0.x = acc0.x * f + pp * va.x;
        acc0.y = acc0.y * f + pp * va.y;
        acc0.z = acc0.z * f + pp * va.z;
        acc0.w = acc0.w * f + pp * va.w;
        acc1.x = acc1.x * f + pp * vb.x;
        acc1.y = acc1.y * f + pp * vb.y;
        acc1.z = acc1.z * f + pp * vb.z;
        acc1.w = acc1.w * f + pp * vb.w;
        m_r = nm;
    }
    int idx = (c * 4 + h) * 1024 + l;
    pm[idx] = m_r;
    ps[idx] = l_r;
    float4* po = (float4*)(pacc + idx * 8);
    po[0] = acc0;
    po[1] = acc1;
}

// ---------------- combine 16 chunks + out-proj + MLP head + sigmoid. One wave per l.
__global__ __launch_bounds__(256) void head_kernel(
    const float* __restrict__ pm, const float* __restrict__ ps, const float* __restrict__ pacc,
    const float* __restrict__ ow, const float* __restrict__ ob,
    const float* __restrict__ d1w, const float* __restrict__ d1b,
    const float* __restrict__ g1, const float* __restrict__ b1,
    const float* __restrict__ d2w, const float* __restrict__ d2b,
    const float* __restrict__ g2, const float* __restrict__ b2,
    const float* __restrict__ d3w, const float* __restrict__ d3b,
    float* __restrict__ out) {
    int wid = threadIdx.x >> 6, j = threadIdx.x & 63;
    int l = blockIdx.x * 4 + wid;
    __shared__ float att_s[4][32], z_s[4][32], r1s[4][64];
    if (j < 32) {
        int h = j >> 3, d = j & 7;
        float M = -1e30f;
#pragma unroll
        for (int c = 0; c < 16; c++) M = fmaxf(M, pm[(c * 4 + h) * 1024 + l]);
        float den = 0.f, num = 0.f;
#pragma unroll
        for (int c = 0; c < 16; c++) {
            int idx = (c * 4 + h) * 1024 + l;
            float e = __expf(pm[idx] - M);
            den += e * ps[idx];
            num += e * pacc[idx * 8 + d];
        }
        att_s[wid][j] = num / den;
    }
    __syncthreads();
    if (j < 32) {
        float a = ob[j];
#pragma unroll
        for (int i = 0; i < 32; i++) a += att_s[wid][i] * ow[j * 32 + i];
        z_s[wid][j] = a;
    }
    __syncthreads();
    const float inv = rsqrtf(1.0f + 1e-5f);
    if (j < 64) {
        float a = d1b[j];
#pragma unroll
        for (int i = 0; i < 32; i++) a += z_s[wid][i] * d1w[j * 32 + i];
        a = a * (g1[j] * inv) + b1[j];
        r1s[wid][j] = fmaxf(a, 0.f);
    }
    __syncthreads();
    if (j < 32) {
        float a = d2b[j];
#pragma unroll
        for (int i = 0; i < 64; i++) a += r1s[wid][i] * d2w[j * 64 + i];
        a = a * (g2[j] * inv) + b2[j];
        float r2 = fmaxf(a, 0.f);
        float p = r2 * d3w[j];
        p += __shfl_down(p, 16);
        p += __shfl_down(p, 8);
        p += __shfl_down(p, 4);
        p += __shfl_down(p, 2);
        p += __shfl_down(p, 1);
        if (j == 0) out[l] = 1.0f / (1.0f + __expf(-(p + d3b[0])));
    }
}

extern "C" void kernel_launch(void* const* d_in, const int* in_sizes, int n_in,
                              void* d_out, int out_size, void* d_ws, size_t ws_size,
                              hipStream_t stream) {
    const float* x      = (const float*)d_in[0];
    const float* emb_w  = (const float*)d_in[1];
    const float* emb_b  = (const float*)d_in[2];
    const float* l1_wih = (const float*)d_in[3];
    const float* l1_whh = (const float*)d_in[4];
    const float* l1_bih = (const float*)d_in[5];
    const float* l1_bhh = (const float*)d_in[6];
    const float* l2_wih = (const float*)d_in[7];
    const float* l2_whh = (const float*)d_in[8];
    const float* l2_bih = (const float*)d_in[9];
    const float* l2_bhh = (const float*)d_in[10];
    const float* attn_w = (const float*)d_in[11];
    const float* attn_b = (const float*)d_in[12];
    const float* attn_ow = (const float*)d_in[13];
    const float* attn_ob = (const float*)d_in[14];
    const float* d1_w  = (const float*)d_in[15];
    const float* d1_b  = (const float*)d_in[16];
    const float* bn1_g = (const float*)d_in[17];
    const float* bn1_b = (const float*)d_in[18];
    const float* d2_w  = (const float*)d_in[19];
    const float* d2_b  = (const float*)d_in[20];
    const float* bn2_g = (const float*)d_in[21];
    const float* bn2_b = (const float*)d_in[22];
    const float* d3_w  = (const float*)d_in[23];
    const float* d3_b  = (const float*)d_in[24];
    float* out = (float*)d_out;

    float* ws   = (float*)d_ws;
    float* A1   = ws;               // 256
    float* C1   = ws + 256;         // 4096
    float* Q    = ws + 4352;        // 32768
    float* K    = ws + 37120;       // 32768
    float* V    = ws + 69888;       // 32768
    float* pm   = ws + 102656;      // 16*4*1024 = 65536
    float* ps   = ws + 168192;      // 65536
    float* pacc = ws + 233728;      // 65536*8 = 524288  (end: 758016 floats ~2.9 MB)

    prep_kernel<<<16, 256, 0, stream>>>(emb_w, emb_b, l1_wih, l1_bih, l1_bhh, A1, C1);
    lstm_kernel<<<512, 256, 0, stream>>>(x, l1_whh, l2_wih, l2_whh, l2_bih, l2_bhh,
                                         attn_w, attn_b, A1, C1, Q, K, V);
    attn_kernel<<<256, 256, 0, stream>>>(Q, K, V, pm, ps, pacc);
    head_kernel<<<256, 256, 0, stream>>>(pm, ps, pacc, attn_ow, attn_ob, d1_w, d1_b,
                                         bn1_g, bn1_b, d2_w, d2_b, bn2_g, bn2_b,
                                         d3_w, d3_b, out);
}